// Round 1
// baseline (921.771 us; speedup 1.0000x reference)
//
#include <hip/hip_runtime.h>
#include <math.h>

#define HID 256
#define PTS 16                 // points per block
#define NSTR 5                 // value, g0, g1, g2, laplacian-sum T
#define ROWS (NSTR*PTS)        // 80
#define PITCH 272              // 256 + 16 halves pad -> 544B row stride, bank-balanced

typedef _Float16 half8 __attribute__((ext_vector_type(8)));
typedef float floatx4 __attribute__((ext_vector_type(4)));

constexpr double PI_D = 3.14159265358979323846;
constexpr float K2F = (float)((343.0/(2.0*PI_D*1000.0))*(343.0/(2.0*PI_D*1000.0)));

__device__ __forceinline__ float tanh_fast(float z) {
  float e = __expf(2.0f*z);
  return 1.0f - 2.0f/(e + 1.0f);
}

// Pack W2,W3 (fp32 row-major [k][n]) into fp16 B-fragment order for
// v_mfma_f32_16x16x32_f16:  out[((kc*16+nt)*64+lane)*8 + j] = W[kc*32+(lane>>4)*8+j][nt*16+(lane&15)]
__global__ void pack_kernel(const float* __restrict__ W2, const float* __restrict__ W3,
                            _Float16* __restrict__ out, float* __restrict__ d_out) {
  int t = blockIdx.x * blockDim.x + threadIdx.x;   // 0..16383
  if (t == 0) d_out[0] = 0.0f;                     // zero the loss accumulator
  int l    = t >> 13;
  int rem  = t & 8191;
  int kc   = rem >> 10;
  int nt   = (rem >> 6) & 15;
  int lane = rem & 63;
  const float* W = l ? W3 : W2;
  int k0 = kc*32 + ((lane >> 4) << 3);
  int n  = nt*16 + (lane & 15);
  _Float16* o = out + (size_t)t * 8;
  #pragma unroll
  for (int j = 0; j < 8; ++j)
    o[j] = (_Float16)W[(size_t)(k0 + j)*HID + n];
}

__global__ __launch_bounds__(256, 3) void helm_kernel(
    const float* __restrict__ inputs,
    const float* __restrict__ W1, const float* __restrict__ b1,
    const float* __restrict__ b2, const float* __restrict__ b3,
    const float* __restrict__ W4, const float* __restrict__ b4,
    const _Float16* __restrict__ Wpack,   // [2][65536] fp16, B-frag packed
    float* __restrict__ out, int N)
{
  __shared__ __align__(16) _Float16 X[ROWS][PITCH];

  const int tid  = threadIdx.x;
  const int lane = tid & 63;
  const int wave = tid >> 6;
  const int m    = lane & 15;   // A-row / B-col / D-col within tile
  const int q    = lane >> 4;   // quad

  const int pbase = blockIdx.x * PTS;

  // ---------------- Layer 1: 3 -> 256 (VALU) ----------------
  {
    const int n = tid;
    float w0 = W1[0*HID + n], w1 = W1[1*HID + n], w2 = W1[2*HID + n];
    float bn = b1[n];
    float wsq = w0*w0 + w1*w1 + w2*w2;
    #pragma unroll
    for (int p = 0; p < PTS; ++p) {
      float x0 = inputs[(size_t)(pbase + p)*3 + 0];
      float x1 = inputs[(size_t)(pbase + p)*3 + 1];
      float x2 = inputs[(size_t)(pbase + p)*3 + 2];
      float z = fmaf(x2, w2, fmaf(x1, w1, fmaf(x0, w0, bn)));
      float a  = tanh_fast(z);
      float dd = 1.0f - a*a;
      X[0*PTS + p][n] = (_Float16)a;
      X[1*PTS + p][n] = (_Float16)(dd*w0);
      X[2*PTS + p][n] = (_Float16)(dd*w1);
      X[3*PTS + p][n] = (_Float16)(dd*w2);
      X[4*PTS + p][n] = (_Float16)(-2.0f*a*dd*wsq);   // sum of d2z/dxi2 terms
    }
  }
  __syncthreads();

  // ---------------- Layers 2,3: 256 -> 256 (MFMA) ----------------
  for (int L = 0; L < 2; ++L) {
    const _Float16* Wp = Wpack + (size_t)L * 65536;
    const float* bb = L ? b3 : b2;

    floatx4 acc[NSTR][4];
    #pragma unroll
    for (int s = 0; s < NSTR; ++s)
      #pragma unroll
      for (int c = 0; c < 4; ++c)
        acc[s][c] = (floatx4){0.0f, 0.0f, 0.0f, 0.0f};

    for (int kc = 0; kc < 8; ++kc) {
      half8 bfrag[4];
      #pragma unroll
      for (int c = 0; c < 4; ++c)
        bfrag[c] = *(const half8*)(Wp + (((size_t)(kc*16 + (wave*4 + c))*64 + lane) << 3));
      half8 afrag[NSTR];
      #pragma unroll
      for (int s = 0; s < NSTR; ++s)
        afrag[s] = *(const half8*)(&X[s*PTS + m][kc*32 + q*8]);
      #pragma unroll
      for (int s = 0; s < NSTR; ++s)
        #pragma unroll
        for (int c = 0; c < 4; ++c)
          acc[s][c] = __builtin_amdgcn_mfma_f32_16x16x32_f16(afrag[s], bfrag[c], acc[s][c], 0, 0, 0);
    }
    __syncthreads();   // everyone done reading X -> safe to overwrite in place

    #pragma unroll
    for (int ct = 0; ct < 4; ++ct) {
      int nn = wave*64 + ct*16 + m;
      float bv = bb[nn];
      #pragma unroll
      for (int r = 0; r < 4; ++r) {
        int p = q*4 + r;          // D-layout: row = quad*4 + reg
        float z  = acc[0][ct][r] + bv;
        float a  = tanh_fast(z);
        float dd = 1.0f - a*a;
        float zp0 = acc[1][ct][r], zp1 = acc[2][ct][r], zp2 = acc[3][ct][r];
        float zpp = acc[4][ct][r];
        float s2  = zp0*zp0 + zp1*zp1 + zp2*zp2;
        X[0*PTS + p][nn] = (_Float16)a;
        X[1*PTS + p][nn] = (_Float16)(dd*zp0);
        X[2*PTS + p][nn] = (_Float16)(dd*zp1);
        X[3*PTS + p][nn] = (_Float16)(dd*zp2);
        X[4*PTS + p][nn] = (_Float16)(fmaf(dd, zpp, -2.0f*a*dd*s2));
      }
    }
    __syncthreads();
  }

  // ---------------- Layer 4: 256 -> 1, residual, reduction ----------------
  float resacc = 0.0f;
  #pragma unroll
  for (int pp = 0; pp < 4; ++pp) {
    int p = wave*4 + pp;
    float su = 0.0f, st = 0.0f;
    #pragma unroll
    for (int jj = 0; jj < 4; ++jj) {
      int nn = lane + jj*64;
      float w4 = W4[nn];
      su = fmaf((float)X[0*PTS + p][nn], w4, su);
      st = fmaf((float)X[4*PTS + p][nn], w4, st);
    }
    #pragma unroll
    for (int off = 32; off; off >>= 1) {
      su += __shfl_down(su, off);
      st += __shfl_down(st, off);
    }
    if (lane == 0) {
      float u   = su + b4[0];
      float res = st + K2F * u;
      resacc = fmaf(res, res, resacc);
    }
  }
  if (lane == 0) atomicAdd(out, resacc * (1.0f / (float)N));
}

extern "C" void kernel_launch(void* const* d_in, const int* in_sizes, int n_in,
                              void* d_out, int out_size, void* d_ws, size_t ws_size,
                              hipStream_t stream) {
  const float* inputs = (const float*)d_in[0];
  const float* W1 = (const float*)d_in[1];
  const float* b1 = (const float*)d_in[2];
  const float* W2 = (const float*)d_in[3];
  const float* b2 = (const float*)d_in[4];
  const float* W3 = (const float*)d_in[5];
  const float* b3 = (const float*)d_in[6];
  const float* W4 = (const float*)d_in[7];
  const float* b4 = (const float*)d_in[8];
  float* out = (float*)d_out;
  _Float16* wp = (_Float16*)d_ws;   // needs 2*65536*2 = 256 KiB of workspace

  int N = in_sizes[0] / 3;          // 262144

  pack_kernel<<<64, 256, 0, stream>>>(W2, W3, wp, out);
  helm_kernel<<<N / PTS, 256, 0, stream>>>(inputs, W1, b1, b2, b3, W4, b4, wp, out, N);
}